// Round 2
// baseline (420.034 us; speedup 1.0000x reference)
//
#include <hip/hip_runtime.h>
#include <cstdint>
#include <cstddef>

// Problem constants (fixed by reference)
#define B_    4
#define S_    4096
#define DIN_  2048
#define DOUT_ 2048
#define R_    16
#define E_    12
// MULTIPLIER * SCALE == 1.0 — folded away.
// Decomposition: out = x @ W_org^T + (x @ W_down^T) @ combined[b]^T
//   -> W_org converted to bf16 ONCE (shared across batches; L2/L3 reuse),
//      rank-16 LoRA term applied as a zero-padded-K MFMA epilogue in the GEMM.

typedef __bf16 bf16x8 __attribute__((ext_vector_type(8)));
typedef float  floatx4 __attribute__((ext_vector_type(4)));

__device__ __forceinline__ unsigned int f2bf(float f) {
  unsigned int u = __builtin_bit_cast(unsigned int, f);
  u += 0x7fffu + ((u >> 16) & 1u);   // round-to-nearest-even
  return u >> 16;
}

__device__ __forceinline__ void async_copy16(const void* g, void* l) {
  __builtin_amdgcn_global_load_lds(
      (const __attribute__((address_space(1))) void*)g,
      (__attribute__((address_space(3))) void*)l,
      16, 0, 0);
}

// ---------------------------------------------------------------------------
// Kernel 1: generic fp32 -> bf16, 8 elems/thread (16B stores). Caller sizes grid.
// ---------------------------------------------------------------------------
__global__ __launch_bounds__(256) void cvt_bf16_kernel(const float* __restrict__ x,
                                                       unsigned short* __restrict__ xb) {
  size_t idx = ((size_t)blockIdx.x * 256 + threadIdx.x) * 8;
  float4 a = *(const float4*)(x + idx);
  float4 b = *(const float4*)(x + idx + 4);
  uint4 o;
  o.x = f2bf(a.x) | (f2bf(a.y) << 16);
  o.y = f2bf(a.z) | (f2bf(a.w) << 16);
  o.z = f2bf(b.x) | (f2bf(b.y) << 16);
  o.w = f2bf(b.z) | (f2bf(b.w) << 16);
  *(uint4*)(xb + idx) = o;
}

// ---------------------------------------------------------------------------
// Kernel 2: combined[b,o,r] = sum_e gate[b,e] * W_up[e,o,r]  -> bf16
// One thread per output element; W_up reads coalesced (r fastest).
// ---------------------------------------------------------------------------
__global__ __launch_bounds__(256) void combined_kernel(const float* __restrict__ gate,
                                                       const float* __restrict__ W_up,
                                                       unsigned short* __restrict__ cmb) {
  const int idx = blockIdx.x * 256 + threadIdx.x;   // over B*DOUT*R = 131072
  const int b   = idx >> 15;                        // DOUT*R = 32768
  const int orr = idx & 32767;
  float s = 0.f;
#pragma unroll
  for (int e = 0; e < E_; ++e)
    s += gate[b * E_ + e] * W_up[(size_t)e * DOUT_ * R_ + orr];
  cmb[idx] = (unsigned short)f2bf(s);
}

// ---------------------------------------------------------------------------
// Kernel 3: lx = xb @ W_down^T  -> bf16  [16384 rows x 16]
// Skinny split-K MFMA: block = 4 waves; waves (2*g+h) handle 16-row group g,
// K-half h (1024 each, 32 steps of 16x16x32). LDS pairwise reduction.
// ---------------------------------------------------------------------------
__global__ __launch_bounds__(256) void lx_kernel(const unsigned short* __restrict__ xb,
                                                 const unsigned short* __restrict__ wdb,
                                                 unsigned short* __restrict__ lxb) {
  const int tid  = threadIdx.x;
  const int lane = tid & 63;
  const int wave = tid >> 6;
  const int grp  = wave >> 1;        // 16-row group within block (0,1)
  const int kh   = wave & 1;         // K-half (0,1)
  const int q    = lane >> 4;
  const int mrow = lane & 15;
  const int row0 = blockIdx.x * 32 + grp * 16;

  floatx4 acc = {};
  const unsigned short* aptr = xb  + (size_t)(row0 + mrow) * DIN_ + kh * 1024 + q * 8;
  const unsigned short* bptr = wdb + (size_t)mrow * DIN_ + kh * 1024 + q * 8;
#pragma unroll 4
  for (int ks = 0; ks < 32; ++ks) {
    bf16x8 av = *(const bf16x8*)(aptr + ks * 32);
    bf16x8 bv = *(const bf16x8*)(bptr + ks * 32);
    acc = __builtin_amdgcn_mfma_f32_16x16x32_bf16(av, bv, acc, 0, 0, 0);
  }

  __shared__ float red[2][64 * 4];
  if (kh == 1) *(floatx4*)&red[grp][lane * 4] = acc;
  __syncthreads();
  if (kh == 0) {
    floatx4 o = *(const floatx4*)&red[grp][lane * 4];
    acc += o;
    // C/D layout: col = lane&15 (= r), row = q*4 + reg
#pragma unroll
    for (int rg = 0; rg < 4; ++rg)
      lxb[(size_t)(row0 + q * 4 + rg) * R_ + mrow] = (unsigned short)f2bf(acc[rg]);
  }
}

// ---------------------------------------------------------------------------
// Kernel 4: per-batch NT GEMM  C[b] = A[b] @ Worg^T + lx[b] @ combined[b]^T
// m97 structure: 128x128 tile, BK=64, global_load_lds width 16, 2-barrier
// K-loop, 4 waves x (4x4 of 16x16x32 MFMA), XOR-swizzled LDS (0 conflicts).
// B-operand (Worg bf16) is SHARED across batches -> L2/L3 reuse.
// Rank-16 LoRA applied as zero-padded-K MFMA epilogue (q>=2 lanes = 0).
// ---------------------------------------------------------------------------
__global__ __launch_bounds__(256) void gemm_kernel(const unsigned short* __restrict__ A,
                                                   const unsigned short* __restrict__ Bw,
                                                   const unsigned short* __restrict__ lx,
                                                   const unsigned short* __restrict__ cmb,
                                                   float* __restrict__ C) {
  constexpr int K = DIN_, N = DOUT_;
  __shared__ unsigned short lds[2 * 128 * 64];   // 32 KiB: A-tile then B-tile
  unsigned short* ldsA = lds;
  unsigned short* ldsB = lds + 128 * 64;

  const int tid  = threadIdx.x;
  const int lane = tid & 63;
  const int wave = tid >> 6;
  const int wm   = wave >> 1;      // wave row (0..1)
  const int wn   = wave & 1;       // wave col (0..1)
  const int q    = lane >> 4;      // quad index 0..3
  const int mrow = lane & 15;

  const int mBase = blockIdx.y * 128;
  const int nBase = blockIdx.x * 128;
  const int batch = blockIdx.z;

  const unsigned short* Ab = A + (size_t)batch * S_ * K;

  floatx4 acc[4][4] = {};

  for (int kt = 0; kt < K / 64; ++kt) {
    const int k0 = kt * 64;
    // ---- stage A and B tiles (128 rows x 64 bf16 each) ----
#pragma unroll
    for (int is = 0; is < 4; ++is) {
      const int p    = is * 4096 + wave * 1024 + lane * 16;  // byte pos in tile
      const int row  = p >> 7;                               // tile row
      const int slot = (p >> 4) & 7;                         // 16B slot in row
      const int ch   = slot ^ (row & 7);                     // swizzled source chunk
      const unsigned short* ga = Ab + (size_t)(mBase + row) * K + k0 + ch * 8;
      const unsigned short* gb = Bw + (size_t)(nBase + row) * K + k0 + ch * 8;
      async_copy16(ga, (char*)ldsA + p);
      async_copy16(gb, (char*)ldsB + p);
    }
    __syncthreads();

    // ---- compute: 2 k-steps of 16x16x32, 16 MFMA each ----
#pragma unroll
    for (int kk = 0; kk < 2; ++kk) {
      bf16x8 af[4], bfr[4];
#pragma unroll
      for (int mt = 0; mt < 4; ++mt) {
        const int r = wm * 64 + mt * 16 + mrow;
        const int c = kk * 4 + q;
        af[mt] = *(const bf16x8*)&ldsA[r * 64 + ((c ^ (r & 7)) << 3)];
      }
#pragma unroll
      for (int nt = 0; nt < 4; ++nt) {
        const int r = wn * 64 + nt * 16 + mrow;
        const int c = kk * 4 + q;
        bfr[nt] = *(const bf16x8*)&ldsB[r * 64 + ((c ^ (r & 7)) << 3)];
      }
#pragma unroll
      for (int mt = 0; mt < 4; ++mt)
#pragma unroll
        for (int nt = 0; nt < 4; ++nt)
          acc[mt][nt] = __builtin_amdgcn_mfma_f32_16x16x32_bf16(af[mt], bfr[nt],
                                                                acc[mt][nt], 0, 0, 0);
    }
    __syncthreads();
  }

  // ---- rank-16 LoRA epilogue: acc += lx_frag @ cmb_frag^T (K=32, hi-half 0) --
  {
    bf16x8 la[4], lb[4];
#pragma unroll
    for (int mt = 0; mt < 4; ++mt) {
      bf16x8 v = {};
      if (q < 2)
        v = *(const bf16x8*)&lx[((size_t)batch * S_ + mBase + wm * 64 + mt * 16 + mrow) * R_ + q * 8];
      la[mt] = v;
    }
#pragma unroll
    for (int nt = 0; nt < 4; ++nt) {
      bf16x8 v = {};
      if (q < 2)
        v = *(const bf16x8*)&cmb[((size_t)batch * DOUT_ + nBase + wn * 64 + nt * 16 + mrow) * R_ + q * 8];
      lb[nt] = v;
    }
#pragma unroll
    for (int mt = 0; mt < 4; ++mt)
#pragma unroll
      for (int nt = 0; nt < 4; ++nt)
        acc[mt][nt] = __builtin_amdgcn_mfma_f32_16x16x32_bf16(la[mt], lb[nt],
                                                              acc[mt][nt], 0, 0, 0);
  }

  // ---- epilogue: C/D layout col=lane&15, row=(lane>>4)*4+reg ----
#pragma unroll
  for (int mt = 0; mt < 4; ++mt) {
#pragma unroll
    for (int nt = 0; nt < 4; ++nt) {
      const int gc  = nBase + wn * 64 + nt * 16 + mrow;
      const int gr0 = mBase + wm * 64 + mt * 16 + q * 4;
#pragma unroll
      for (int rg = 0; rg < 4; ++rg)
        C[((size_t)batch * S_ + gr0 + rg) * N + gc] = acc[mt][nt][rg];
    }
  }
}

// ---------------------------------------------------------------------------
extern "C" void kernel_launch(void* const* d_in, const int* in_sizes, int n_in,
                              void* d_out, int out_size, void* d_ws, size_t ws_size,
                              hipStream_t stream) {
  const float* x      = (const float*)d_in[0];
  const float* gate   = (const float*)d_in[1];
  const float* W_org  = (const float*)d_in[2];
  const float* W_down = (const float*)d_in[3];
  const float* W_up   = (const float*)d_in[4];
  float* out = (float*)d_out;

  // workspace layout (ushort elems):
  unsigned short* xb   = (unsigned short*)d_ws;             // 33,554,432
  unsigned short* worg = xb   + (size_t)B_ * S_ * DIN_;     //  4,194,304
  unsigned short* wdb  = worg + (size_t)DOUT_ * DIN_;       //     32,768
  unsigned short* lxb  = wdb  + (size_t)R_ * DIN_;          //    262,144
  unsigned short* cmb  = lxb  + (size_t)B_ * S_ * R_;       //    131,072

  // 1) fp32 -> bf16 conversions
  cvt_bf16_kernel<<<(B_ * S_ * DIN_) / 2048, 256, 0, stream>>>(x, xb);
  cvt_bf16_kernel<<<(DOUT_ * DIN_) / 2048, 256, 0, stream>>>(W_org, worg);
  cvt_bf16_kernel<<<(R_ * DIN_) / 2048, 256, 0, stream>>>(W_down, wdb);

  // 2) combined[b] = gate[b] . W_up   (bf16)
  combined_kernel<<<(B_ * DOUT_ * R_) / 256, 256, 0, stream>>>(gate, W_up, cmb);

  // 3) lx = xb @ W_down^T  (bf16)
  lx_kernel<<<(B_ * S_) / 32, 256, 0, stream>>>(xb, wdb, lxb);

  // 4) out[b] = xb[b] @ Worg^T + lx[b] @ combined[b]^T  (fp32 out)
  gemm_kernel<<<dim3(DOUT_ / 128, S_ / 128, B_), 256, 0, stream>>>(xb, worg, lxb, cmb, out);
}

// Round 3
// 397.881 us; speedup vs baseline: 1.0557x; 1.0557x over previous
//
#include <hip/hip_runtime.h>
#include <cstdint>
#include <cstddef>

// Problem constants (fixed by reference)
#define B_    4
#define S_    4096
#define DIN_  2048
#define DOUT_ 2048
#define R_    16
#define E_    12
// MULTIPLIER * SCALE == 1.0 — folded away.
// Decomposition: out = x @ W_org^T + (x @ W_down^T) @ combined[b]^T
// Single fused GEMM over M = B*S = 16384 (batch folded into rows; W_org shared).
// Round 3: MFMA shape 32x32x16 (2495 TF ubench vs 2176 for 16x16x32, half the
// instruction count per K-step); LoRA epilogue is 4 unpadded K=16 MFMAs.

typedef __bf16 bf16x8  __attribute__((ext_vector_type(8)));
typedef float  floatx4  __attribute__((ext_vector_type(4)));
typedef float  floatx16 __attribute__((ext_vector_type(16)));

__device__ __forceinline__ unsigned int f2bf(float f) {
  unsigned int u = __builtin_bit_cast(unsigned int, f);
  u += 0x7fffu + ((u >> 16) & 1u);   // round-to-nearest-even
  return u >> 16;
}

__device__ __forceinline__ void async_copy16(const void* g, void* l) {
  __builtin_amdgcn_global_load_lds(
      (const __attribute__((address_space(1))) void*)g,
      (__attribute__((address_space(3))) void*)l,
      16, 0, 0);
}

// ---------------------------------------------------------------------------
// Kernel 1: x fp32 -> bf16, 8 elems/thread (16B stores).
// ---------------------------------------------------------------------------
__global__ __launch_bounds__(256) void cvt_x_kernel(const float* __restrict__ x,
                                                    unsigned short* __restrict__ xb) {
  size_t idx = ((size_t)blockIdx.x * 256 + threadIdx.x) * 8;
  float4 a = *(const float4*)(x + idx);
  float4 b = *(const float4*)(x + idx + 4);
  uint4 o;
  o.x = f2bf(a.x) | (f2bf(a.y) << 16);
  o.y = f2bf(a.z) | (f2bf(a.w) << 16);
  o.z = f2bf(b.x) | (f2bf(b.y) << 16);
  o.w = f2bf(b.z) | (f2bf(b.w) << 16);
  *(uint4*)(xb + idx) = o;
}

// ---------------------------------------------------------------------------
// Kernel 2 (fused prep): blocks [0,2048): W_org cvt; [2048,2064): W_down cvt;
// [2064,2576): combined[b,o,r] = sum_e gate[b,e]*W_up[e,o,r]. Block-uniform
// branching only.
// ---------------------------------------------------------------------------
__global__ __launch_bounds__(256) void prep_misc_kernel(const float* __restrict__ W_org,
                                                        const float* __restrict__ W_down,
                                                        const float* __restrict__ gate,
                                                        const float* __restrict__ W_up,
                                                        unsigned short* __restrict__ worg,
                                                        unsigned short* __restrict__ wdb,
                                                        unsigned short* __restrict__ cmb) {
  const int bid = blockIdx.x;
  const int tid = threadIdx.x;
  if (bid < 2064) {
    const float* src;
    unsigned short* dst;
    size_t idx;
    if (bid < 2048) { src = W_org;  dst = worg; idx = ((size_t)bid * 256 + tid) * 8; }
    else            { src = W_down; dst = wdb;  idx = ((size_t)(bid - 2048) * 256 + tid) * 8; }
    float4 a = *(const float4*)(src + idx);
    float4 b = *(const float4*)(src + idx + 4);
    uint4 o;
    o.x = f2bf(a.x) | (f2bf(a.y) << 16);
    o.y = f2bf(a.z) | (f2bf(a.w) << 16);
    o.z = f2bf(b.x) | (f2bf(b.y) << 16);
    o.w = f2bf(b.z) | (f2bf(b.w) << 16);
    *(uint4*)(dst + idx) = o;
  } else {
    const int idx = (bid - 2064) * 256 + tid;    // over B*DOUT*R = 131072
    const int b   = idx >> 15;                   // DOUT*R = 32768
    const int orr = idx & 32767;
    float s = 0.f;
#pragma unroll
    for (int e = 0; e < E_; ++e)
      s += gate[b * E_ + e] * W_up[(size_t)e * DOUT_ * R_ + orr];
    cmb[idx] = (unsigned short)f2bf(s);
  }
}

// ---------------------------------------------------------------------------
// Kernel 3: lx = xb @ W_down^T  -> bf16  [16384 rows x 16]  (proven r2 version)
// ---------------------------------------------------------------------------
__global__ __launch_bounds__(256) void lx_kernel(const unsigned short* __restrict__ xb,
                                                 const unsigned short* __restrict__ wdb,
                                                 unsigned short* __restrict__ lxb) {
  const int tid  = threadIdx.x;
  const int lane = tid & 63;
  const int wave = tid >> 6;
  const int grp  = wave >> 1;        // 16-row group within block (0,1)
  const int kh   = wave & 1;         // K-half (0,1)
  const int q    = lane >> 4;
  const int mrow = lane & 15;
  const int row0 = blockIdx.x * 32 + grp * 16;

  floatx4 acc = {};
  const unsigned short* aptr = xb  + (size_t)(row0 + mrow) * DIN_ + kh * 1024 + q * 8;
  const unsigned short* bptr = wdb + (size_t)mrow * DIN_ + kh * 1024 + q * 8;
#pragma unroll 4
  for (int ks = 0; ks < 32; ++ks) {
    bf16x8 av = *(const bf16x8*)(aptr + ks * 32);
    bf16x8 bv = *(const bf16x8*)(bptr + ks * 32);
    acc = __builtin_amdgcn_mfma_f32_16x16x32_bf16(av, bv, acc, 0, 0, 0);
  }

  __shared__ float red[2][64 * 4];
  if (kh == 1) *(floatx4*)&red[grp][lane * 4] = acc;
  __syncthreads();
  if (kh == 0) {
    floatx4 o = *(const floatx4*)&red[grp][lane * 4];
    acc += o;
    // 16x16 C/D layout: col = lane&15 (= r), row = q*4 + reg
#pragma unroll
    for (int rg = 0; rg < 4; ++rg)
      lxb[(size_t)(row0 + q * 4 + rg) * R_ + mrow] = (unsigned short)f2bf(acc[rg]);
  }
}

// ---------------------------------------------------------------------------
// Kernel 4: fused NT GEMM  C = xb @ worg^T + lx @ cmb[batch]^T
// M = 16384 (batch = m>>12), N = 2048, K = 2048. 128x128 tile, BK=64,
// global_load_lds width 16, XOR-swizzled LDS, 4 waves x (2x2 of 32x32x16).
//   A-frag: row = lane&31, k = (lane>>5)*8 + j
//   C/D   : col = lane&31, row = (reg&3) + 8*(reg>>2) + 4*(lane>>5)   [m74/m101]
// ---------------------------------------------------------------------------
__global__ __launch_bounds__(256) void gemm_kernel(const unsigned short* __restrict__ A,
                                                   const unsigned short* __restrict__ Bw,
                                                   const unsigned short* __restrict__ lx,
                                                   const unsigned short* __restrict__ cmb,
                                                   float* __restrict__ C) {
  constexpr int K = DIN_, N = DOUT_;
  __shared__ unsigned short lds[2 * 128 * 64];   // 32 KiB: A-tile then B-tile
  unsigned short* ldsA = lds;
  unsigned short* ldsB = lds + 128 * 64;

  const int tid  = threadIdx.x;
  const int lane = tid & 63;
  const int wave = tid >> 6;
  const int wm   = wave >> 1;      // wave row (0..1)
  const int wn   = wave & 1;       // wave col (0..1)
  const int g    = lane >> 5;      // lane group (0..1) -> K-half of frag
  const int mrow = lane & 31;

  const int mBase = blockIdx.y * 128;
  const int nBase = blockIdx.x * 128;
  const int batch = blockIdx.y >> 5;   // 4096 rows per batch; tiles never straddle

  floatx16 acc[2][2] = {};

  for (int kt = 0; kt < K / 64; ++kt) {
    const int k0 = kt * 64;
    // ---- stage A and B tiles (128 rows x 64 bf16 each), swizzled ----
#pragma unroll
    for (int is = 0; is < 4; ++is) {
      const int p    = is * 4096 + wave * 1024 + lane * 16;  // byte pos in tile
      const int row  = p >> 7;                               // tile row
      const int slot = (p >> 4) & 7;                         // 16B slot in row
      const int ch   = slot ^ (row & 7);                     // swizzled source chunk
      const unsigned short* ga = A  + (size_t)(mBase + row) * K + k0 + ch * 8;
      const unsigned short* gb = Bw + (size_t)(nBase + row) * K + k0 + ch * 8;
      async_copy16(ga, (char*)ldsA + p);
      async_copy16(gb, (char*)ldsB + p);
    }
    __syncthreads();

    // ---- compute: 4 k-chunks of 32x32x16, 4 MFMA each ----
#pragma unroll
    for (int kc = 0; kc < 4; ++kc) {
      const int c = kc * 2 + g;          // 16B chunk index 0..7
      bf16x8 af[2], bfr[2];
#pragma unroll
      for (int mt = 0; mt < 2; ++mt) {
        const int r = wm * 64 + mt * 32 + mrow;
        af[mt] = *(const bf16x8*)&ldsA[r * 64 + ((c ^ (r & 7)) << 3)];
      }
#pragma unroll
      for (int nt = 0; nt < 2; ++nt) {
        const int r = wn * 64 + nt * 32 + mrow;
        bfr[nt] = *(const bf16x8*)&ldsB[r * 64 + ((c ^ (r & 7)) << 3)];
      }
#pragma unroll
      for (int mt = 0; mt < 2; ++mt)
#pragma unroll
        for (int nt = 0; nt < 2; ++nt)
          acc[mt][nt] = __builtin_amdgcn_mfma_f32_32x32x16_bf16(af[mt], bfr[nt],
                                                                acc[mt][nt], 0, 0, 0);
    }
    __syncthreads();
  }

  // ---- rank-16 LoRA epilogue: K=16 == R, no padding needed ----
  {
    bf16x8 la[2], lb[2];
#pragma unroll
    for (int mt = 0; mt < 2; ++mt)
      la[mt] = *(const bf16x8*)&lx[(size_t)(mBase + wm * 64 + mt * 32 + mrow) * R_ + g * 8];
#pragma unroll
    for (int nt = 0; nt < 2; ++nt)
      lb[nt] = *(const bf16x8*)&cmb[((size_t)batch * DOUT_ + nBase + wn * 64 + nt * 32 + mrow) * R_ + g * 8];
#pragma unroll
    for (int mt = 0; mt < 2; ++mt)
#pragma unroll
      for (int nt = 0; nt < 2; ++nt)
        acc[mt][nt] = __builtin_amdgcn_mfma_f32_32x32x16_bf16(la[mt], lb[nt],
                                                              acc[mt][nt], 0, 0, 0);
  }

  // ---- store: col = nBase.. + lane&31, rows via reg map ----
#pragma unroll
  for (int mt = 0; mt < 2; ++mt) {
#pragma unroll
    for (int nt = 0; nt < 2; ++nt) {
      const int gc  = nBase + wn * 64 + nt * 32 + mrow;
      const int gr0 = mBase + wm * 64 + mt * 32 + g * 4;
#pragma unroll
      for (int rg = 0; rg < 16; ++rg) {
        const int grow = gr0 + (rg & 3) + 8 * (rg >> 2);
        C[(size_t)grow * N + gc] = acc[mt][nt][rg];
      }
    }
  }
}

// ---------------------------------------------------------------------------
extern "C" void kernel_launch(void* const* d_in, const int* in_sizes, int n_in,
                              void* d_out, int out_size, void* d_ws, size_t ws_size,
                              hipStream_t stream) {
  const float* x      = (const float*)d_in[0];
  const float* gate   = (const float*)d_in[1];
  const float* W_org  = (const float*)d_in[2];
  const float* W_down = (const float*)d_in[3];
  const float* W_up   = (const float*)d_in[4];
  float* out = (float*)d_out;

  // workspace layout (ushort elems):
  unsigned short* xb   = (unsigned short*)d_ws;             // 33,554,432
  unsigned short* worg = xb   + (size_t)B_ * S_ * DIN_;     //  4,194,304
  unsigned short* wdb  = worg + (size_t)DOUT_ * DIN_;       //     32,768
  unsigned short* lxb  = wdb  + (size_t)R_ * DIN_;          //    262,144
  unsigned short* cmb  = lxb  + (size_t)B_ * S_ * R_;       //    131,072

  // 1) x -> bf16
  cvt_x_kernel<<<(B_ * S_ * DIN_) / 2048, 256, 0, stream>>>(x, xb);

  // 2) fused prep: W_org cvt + W_down cvt + combined
  prep_misc_kernel<<<2576, 256, 0, stream>>>(W_org, W_down, gate, W_up, worg, wdb, cmb);

  // 3) lx = xb @ W_down^T  (bf16)
  lx_kernel<<<(B_ * S_) / 32, 256, 0, stream>>>(xb, wdb, lxb);

  // 4) out = xb @ worg^T + lx @ cmb[batch]^T  (fp32 out)
  gemm_kernel<<<dim3(DOUT_ / 128, (B_ * S_) / 128), 256, 0, stream>>>(xb, worg, lxb, cmb, out);
}